// Round 2
// baseline (613.018 us; speedup 1.0000x reference)
//
#include <hip/hip_runtime.h>
#include <hip/hip_bf16.h>

typedef __bf16 bfv8 __attribute__((ext_vector_type(8)));
typedef float f32x4 __attribute__((ext_vector_type(4)));

#define MFMA(a,b,c) __builtin_amdgcn_mfma_f32_16x16x32_bf16((a),(b),(c),0,0,0)

constexpr int XW_LD = 392;   // 384+8 pad: 784B rows, 16B aligned, balanced banks
constexpr int QK_LD = 40;    // 32+8: 80B rows
constexpr int VT_LD = 72;    // 64+8: 144B rows

// Transposed bf16 weights: qT[col][k] = w_qkv[k][col], pT[col][k] = w_proj[k][col]
__global__ __launch_bounds__(256)
void prep_weights(const float* __restrict__ w_qkv, const float* __restrict__ w_proj,
                  unsigned short* __restrict__ qT, unsigned short* __restrict__ pT)
{
    int i = blockIdx.x * 256 + threadIdx.x;
    const int NQ = 1152 * 384;
    if (i < NQ) {
        int c = i / 384, k = i - c * 384;
        __bf16 h = (__bf16)w_qkv[k * 1152 + c];
        qT[i] = *(unsigned short*)&h;
    } else {
        int j = i - NQ;
        if (j < 384 * 384) {
            int c = j / 384, k = j - c * 384;
            __bf16 h = (__bf16)w_proj[k * 384 + c];
            pT[j] = *(unsigned short*)&h;
        }
    }
}

__device__ __forceinline__ unsigned int pkbf(float a, float b) {
    __bf16 x = (__bf16)a, y = (__bf16)b;
    unsigned short lo = *(unsigned short*)&x, hi = *(unsigned short*)&y;
    return ((unsigned int)hi << 16) | lo;
}

// One WG per 8x8 window; 512 thr = 8 waves. MFMA 16x16x32 layouts (m89/m92):
//  a_frag lane l elem j = A[l&15][(l>>4)*8+j]
//  b_frag lane l elem j = B[(l>>4)*8+j][l&15]
//  d      lane l reg  r = D[(l>>4)*4+r][l&15]
__global__ __launch_bounds__(512)
void win_attn(const float* __restrict__ x,
              const float* __restrict__ b_qkv,
              const float* __restrict__ b_proj,
              const unsigned short* __restrict__ qT_,
              const unsigned short* __restrict__ pT_,
              float* __restrict__ out)
{
    __shared__ __bf16 sX[64 * XW_LD];           // 50176 B
    __shared__ __bf16 sO[64 * XW_LD];           // 50176 B
    __shared__ __bf16 sQ[2][2 * 64 * QK_LD];    // dbuf: 2 x 10240 B
    __shared__ __bf16 sK[2][2 * 64 * QK_LD];    // dbuf: 2 x 10240 B
    __shared__ __bf16 sVT[2][2 * 32 * VT_LD];   // dbuf: 2 x  9216 B
    // total 159744 B

    const __bf16* wqkvT  = (const __bf16*)qT_;
    const __bf16* wprojT = (const __bf16*)pT_;

    const int wid  = blockIdx.x;
    const int bb   = wid >> 6;
    const int wy   = (wid >> 3) & 7;
    const int wx   = wid & 7;
    const int tid  = threadIdx.x;
    const int lane = tid & 63;
    const int wv   = tid >> 6;
    const int lr   = lane & 15;
    const int lg   = lane >> 4;
    const int k8   = lg * 8;

    const size_t gbase = ((size_t)(bb * 64 + wy * 8) * 64 + wx * 8) * 384;

    // ---- stage x window -> sX (bf16, packed 8B LDS writes) ----
    {
        const float* xb = x + gbase;
        for (int i = tid; i < 64 * 96; i += 512) {
            int t  = i / 96;
            int c4 = (i - t * 96) * 4;
            const float4 v = *(const float4*)(xb + (size_t)((t >> 3) * 64 + (t & 7)) * 384 + c4);
            *(uint2*)&sX[t * XW_LD + c4] = make_uint2(pkbf(v.x, v.y), pkbf(v.z, v.w));
        }
    }
    __syncthreads();

    const int mh = wv >> 2;   // QKV: m-half (tokens mh*32..mh*32+31)
    const int ng = wv & 3;    // QKV: n-group -> tiles {Q:ng, K:4+ng, V:8+ng}

    // ---- QKV GEMM step: wave computes 2m x {1Q,1K,1V} tiles, K=384 ----
    auto qkv_step = [&](int hp, int bi) {
        const int hh = ng >> 1, dt = ng & 1;
        const int cQ = (hp * 2 + hh) * 32 + dt * 16;
        const int cK = cQ + 384, cV = cQ + 768;
        const __bf16* bQ = wqkvT + (size_t)(cQ + lr) * 384 + k8;
        const __bf16* bK = wqkvT + (size_t)(cK + lr) * 384 + k8;
        const __bf16* bV = wqkvT + (size_t)(cV + lr) * 384 + k8;
        const __bf16* ax = &sX[(mh * 32 + lr) * XW_LD + k8];
        f32x4 aq0{}, aq1{}, ak0{}, ak1{}, av0{}, av1{};
        #pragma unroll
        for (int kk = 0; kk < 12; ++kk) {
            bfv8 wq  = *(const bfv8*)(bQ + kk * 32);
            bfv8 wk  = *(const bfv8*)(bK + kk * 32);
            bfv8 wvv = *(const bfv8*)(bV + kk * 32);
            bfv8 a0  = *(const bfv8*)(ax + kk * 32);
            bfv8 a1  = *(const bfv8*)(ax + 16 * XW_LD + kk * 32);
            aq0 = MFMA(a0, wq, aq0);   aq1 = MFMA(a1, wq, aq1);
            ak0 = MFMA(a0, wk, ak0);   ak1 = MFMA(a1, wk, ak1);
            av0 = MFMA(wvv, a0, av0);  av1 = MFMA(wvv, a1, av1);   // swapped -> V^T tile
        }
        const float SC = 0.17677669529663687f;
        const float bq = b_qkv[cQ + lr];
        const float bk = b_qkv[cK + lr];
        __bf16* q_ = sQ[bi]; __bf16* k_ = sK[bi]; __bf16* v_ = sVT[bi];
        #pragma unroll
        for (int r = 0; r < 4; ++r) {
            const int t0 = mh * 32 + lg * 4 + r;
            q_[(hh * 64 + t0) * QK_LD + dt * 16 + lr]      = (__bf16)((aq0[r] + bq) * SC);
            q_[(hh * 64 + t0 + 16) * QK_LD + dt * 16 + lr] = (__bf16)((aq1[r] + bq) * SC);
            k_[(hh * 64 + t0) * QK_LD + dt * 16 + lr]      = (__bf16)(ak0[r] + bk);
            k_[(hh * 64 + t0 + 16) * QK_LD + dt * 16 + lr] = (__bf16)(ak1[r] + bk);
            const float bvr = b_qkv[cV + lg * 4 + r];
            // D of swapped mfma: lane reg r = V^T[d_local = lg*4+r][token = mt*16+lr]
            v_[(hh * 32 + dt * 16 + lg * 4 + r) * VT_LD + mh * 32 + lr]      = (__bf16)(av0[r] + bvr);
            v_[(hh * 32 + dt * 16 + lg * 4 + r) * VT_LD + mh * 32 + 16 + lr] = (__bf16)(av1[r] + bvr);
        }
    };

    // ---- attention step: wave = head (wv>>2) x 16-query strip (wv&3) ----
    // S^T = mfma(K,Q): lane owns query t = ms*16+lr, holds S[t][n*16+lg*4+r]
    auto attn_step = [&](int hp, int bi) {
        const __bf16* q_ = sQ[bi]; const __bf16* k_ = sK[bi]; const __bf16* v_ = sVT[bi];
        const int ah = wv >> 2;
        const int ms = wv & 3;
        const bfv8 qf = *(const bfv8*)&q_[(ah * 64 + ms * 16 + lr) * QK_LD + k8];
        f32x4 st[4];
        #pragma unroll
        for (int n = 0; n < 4; ++n) {
            bfv8 kf = *(const bfv8*)&k_[(ah * 64 + n * 16 + lr) * QK_LD + k8];
            f32x4 z{};
            st[n] = MFMA(kf, qf, z);
        }
        float mx = -1e30f;
        #pragma unroll
        for (int n = 0; n < 4; ++n)
            #pragma unroll
            for (int r = 0; r < 4; ++r) mx = fmaxf(mx, st[n][r]);
        mx = fmaxf(mx, __shfl_xor(mx, 16, 64));
        mx = fmaxf(mx, __shfl_xor(mx, 32, 64));
        float sum = 0.f;
        #pragma unroll
        for (int n = 0; n < 4; ++n)
            #pragma unroll
            for (int r = 0; r < 4; ++r) { st[n][r] = __expf(st[n][r] - mx); sum += st[n][r]; }
        sum += __shfl_xor(sum, 16, 64);
        sum += __shfl_xor(sum, 32, 64);
        const float rinv = 1.f / sum;
        unsigned int pk[4][2];
        #pragma unroll
        for (int n = 0; n < 4; ++n) {
            pk[n][0] = pkbf(st[n][0] * rinv, st[n][1] * rinv);
            pk[n][1] = pkbf(st[n][2] * rinv, st[n][3] * rinv);
        }
        // P D-layout -> A-frag: dest lane (lg,lr) dword w <- lane (2(lg&1)+(w>>1))*16+lr,
        // register pk[2ks + (lg>>1)][w&1]
        const int abase = ((lg & 1) * 32 + lr) * 4;
        f32x4 o0{}, o1{};
        #pragma unroll
        for (int ks = 0; ks < 2; ++ks) {
            union { unsigned int u[4]; bfv8 v; } cv;
            #pragma unroll
            for (int w = 0; w < 4; ++w) {
                const int addr = abase + (w >> 1) * 64;
                const int lo_ = __builtin_amdgcn_ds_bpermute(addr, (int)pk[2 * ks][w & 1]);
                const int hi_ = __builtin_amdgcn_ds_bpermute(addr, (int)pk[2 * ks + 1][w & 1]);
                cv.u[w] = (unsigned int)((lg & 2) ? hi_ : lo_);
            }
            const bfv8 vf0 = *(const bfv8*)&v_[(ah * 32 + lr) * VT_LD + ks * 32 + k8];
            const bfv8 vf1 = *(const bfv8*)&v_[(ah * 32 + 16 + lr) * VT_LD + ks * 32 + k8];
            o0 = MFMA(cv.v, vf0, o0);
            o1 = MFMA(cv.v, vf1, o1);
        }
        const int cb = (hp * 2 + ah) * 32;
        #pragma unroll
        for (int r = 0; r < 4; ++r) {
            sO[(ms * 16 + lg * 4 + r) * XW_LD + cb + lr]      = (__bf16)o0[r];
            sO[(ms * 16 + lg * 4 + r) * XW_LD + cb + 16 + lr] = (__bf16)o1[r];
        }
    };

    // ---- pipelined head-pair loop: 1 barrier per hp ----
    qkv_step(0, 0);
    __syncthreads();
    #pragma unroll 1
    for (int hp = 0; hp < 6; ++hp) {
        if (hp < 5) qkv_step(hp + 1, (hp + 1) & 1);   // writes buf^1
        attn_step(hp, hp & 1);                        // reads buf, writes sO
        __syncthreads();
    }

    // ---- projection: Out = sO(64x384) @ Wp + b; wave = 3 n-tiles, 4 m-tiles ----
    {
        const int nb = wv * 48;
        const __bf16* bp0 = wprojT + (size_t)(nb + lr) * 384 + k8;
        const __bf16* bp1 = bp0 + (size_t)16 * 384;
        const __bf16* bp2 = bp0 + (size_t)32 * 384;
        f32x4 acc[4][3];
        #pragma unroll
        for (int m = 0; m < 4; ++m)
            #pragma unroll
            for (int j = 0; j < 3; ++j) acc[m][j] = f32x4{0.f, 0.f, 0.f, 0.f};
        #pragma unroll
        for (int kk = 0; kk < 12; ++kk) {
            const bfv8 b0 = *(const bfv8*)(bp0 + kk * 32);
            const bfv8 b1 = *(const bfv8*)(bp1 + kk * 32);
            const bfv8 b2 = *(const bfv8*)(bp2 + kk * 32);
            #pragma unroll
            for (int m = 0; m < 4; ++m) {
                const bfv8 af = *(const bfv8*)&sO[(m * 16 + lr) * XW_LD + kk * 32 + k8];
                acc[m][0] = MFMA(af, b0, acc[m][0]);
                acc[m][1] = MFMA(af, b1, acc[m][1]);
                acc[m][2] = MFMA(af, b2, acc[m][2]);
            }
        }
        float* ob = out + gbase;
        const float bb0 = b_proj[nb + lr], bb1 = b_proj[nb + 16 + lr], bb2 = b_proj[nb + 32 + lr];
        #pragma unroll
        for (int m = 0; m < 4; ++m)
            #pragma unroll
            for (int r = 0; r < 4; ++r) {
                const int t = m * 16 + lg * 4 + r;
                float* op = ob + (size_t)((t >> 3) * 64 + (t & 7)) * 384 + nb;
                op[lr]      = acc[m][0][r] + bb0;
                op[16 + lr] = acc[m][1][r] + bb1;
                op[32 + lr] = acc[m][2][r] + bb2;
            }
    }
}

extern "C" void kernel_launch(void* const* d_in, const int* in_sizes, int n_in,
                              void* d_out, int out_size, void* d_ws, size_t ws_size,
                              hipStream_t stream)
{
    const float* x      = (const float*)d_in[0];
    const float* w_qkv  = (const float*)d_in[1];
    const float* b_qkv  = (const float*)d_in[2];
    const float* w_proj = (const float*)d_in[3];
    const float* b_proj = (const float*)d_in[4];
    float* out = (float*)d_out;

    unsigned short* qT = (unsigned short*)d_ws;
    unsigned short* pT = qT + 1152 * 384;

    const int NPREP = 1152 * 384 + 384 * 384;
    prep_weights<<<(NPREP + 255) / 256, 256, 0, stream>>>(w_qkv, w_proj, qT, pT);
    win_attn<<<2048, 512, 0, stream>>>(x, b_qkv, b_proj, qT, pT, out);
}

// Round 3
// 519.817 us; speedup vs baseline: 1.1793x; 1.1793x over previous
//
#include <hip/hip_runtime.h>
#include <hip/hip_bf16.h>

typedef __bf16 bfv8 __attribute__((ext_vector_type(8)));
typedef float f32x4 __attribute__((ext_vector_type(4)));

#define MFMA(a,b,c) __builtin_amdgcn_mfma_f32_16x16x32_bf16((a),(b),(c),0,0,0)

constexpr int XW_LD = 392;   // 384+8 pad: 784B rows, 16B aligned
constexpr int QK_LD = 40;    // 32+8: 80B rows
constexpr int VT_LD = 72;    // 64+8: 144B rows

// Transposed bf16 weights: qT[col][k] = w_qkv[k][col], pT[col][k] = w_proj[k][col]
__global__ __launch_bounds__(256)
void prep_weights(const float* __restrict__ w_qkv, const float* __restrict__ w_proj,
                  unsigned short* __restrict__ qT, unsigned short* __restrict__ pT)
{
    int i = blockIdx.x * 256 + threadIdx.x;
    const int NQ = 1152 * 384;
    if (i < NQ) {
        int c = i / 384, k = i - c * 384;
        __bf16 h = (__bf16)w_qkv[k * 1152 + c];
        qT[i] = *(unsigned short*)&h;
    } else {
        int j = i - NQ;
        if (j < 384 * 384) {
            int c = j / 384, k = j - c * 384;
            __bf16 h = (__bf16)w_proj[k * 384 + c];
            pT[j] = *(unsigned short*)&h;
        }
    }
}

__device__ __forceinline__ unsigned int pkbf(float a, float b) {
    __bf16 x = (__bf16)a, y = (__bf16)b;
    unsigned short lo = *(unsigned short*)&x, hi = *(unsigned short*)&y;
    return ((unsigned int)hi << 16) | lo;
}

// One WG per 8x8 window; 512 thr = 8 waves; LDS 79872 B -> 2 WG/CU.
// MFMA 16x16x32 layouts (m89/m92):
//  a_frag lane l elem j = A[l&15][(l>>4)*8+j]
//  b_frag lane l elem j = B[(l>>4)*8+j][l&15]
//  d      lane l reg  r = D[(l>>4)*4+r][l&15]
__global__ __launch_bounds__(512, 4)
void win_attn(const float* __restrict__ x,
              const float* __restrict__ b_qkv,
              const float* __restrict__ b_proj,
              const unsigned short* __restrict__ qT_,
              const unsigned short* __restrict__ pT_,
              float* __restrict__ out)
{
    __shared__ __bf16 sX[64 * XW_LD];        // 50176 B; reused as sO after last head pair
    __shared__ __bf16 sQ[2 * 64 * QK_LD];    // 10240 B
    __shared__ __bf16 sK[2 * 64 * QK_LD];    // 10240 B
    __shared__ __bf16 sVT[2 * 32 * VT_LD];   //  9216 B
    // total 79872 B -> 2 WGs/CU (159744 <= 163840)

    const __bf16* wqkvT  = (const __bf16*)qT_;
    const __bf16* wprojT = (const __bf16*)pT_;

    const int wid  = blockIdx.x;
    const int bb   = wid >> 6;
    const int wy   = (wid >> 3) & 7;
    const int wx   = wid & 7;
    const int tid  = threadIdx.x;
    const int lane = tid & 63;
    const int wv   = tid >> 6;
    const int lr   = lane & 15;
    const int lg   = lane >> 4;
    const int k8   = lg * 8;

    const size_t gbase = ((size_t)(bb * 64 + wy * 8) * 64 + wx * 8) * 384;

    // ---- stage x window -> sX (bf16, 8B packed LDS writes) ----
    {
        const float* xb = x + gbase;
        for (int i = tid; i < 64 * 96; i += 512) {
            int t  = i / 96;
            int c4 = (i - t * 96) * 4;
            const float4 v = *(const float4*)(xb + (size_t)((t >> 3) * 64 + (t & 7)) * 384 + c4);
            *(uint2*)&sX[t * XW_LD + c4] = make_uint2(pkbf(v.x, v.y), pkbf(v.z, v.w));
        }
    }
    __syncthreads();

    const int mh = wv >> 2;   // QKV: m-half
    const int ng = wv & 3;    // QKV: n-group -> {Q,K,V} column tile
    const int ah = wv >> 2;   // attn: head-local
    const int ms = wv & 3;    // attn: 16-query strip

    unsigned int opk[6][4];   // attention output, bf16-packed; static indices only

    #pragma unroll
    for (int hp = 0; hp < 6; ++hp) {
        // ---- QKV: wave computes 2m x {1Q,1K,1V} 16-col tiles, K=384 ----
        {
            const int hh = ng >> 1, dt = ng & 1;
            const int cQ = (hp * 2 + hh) * 32 + dt * 16;
            const int cK = cQ + 384, cV = cQ + 768;
            const __bf16* bQ = wqkvT + (size_t)(cQ + lr) * 384 + k8;
            const __bf16* bK = wqkvT + (size_t)(cK + lr) * 384 + k8;
            const __bf16* bV = wqkvT + (size_t)(cV + lr) * 384 + k8;
            const __bf16* ax = &sX[(mh * 32 + lr) * XW_LD + k8];
            f32x4 aq0{}, aq1{}, ak0{}, ak1{}, av0{}, av1{};
            __builtin_amdgcn_s_setprio(1);
            #pragma unroll
            for (int kk = 0; kk < 12; ++kk) {
                bfv8 wq  = *(const bfv8*)(bQ + kk * 32);
                bfv8 wk  = *(const bfv8*)(bK + kk * 32);
                bfv8 wvv = *(const bfv8*)(bV + kk * 32);
                bfv8 a0  = *(const bfv8*)(ax + kk * 32);
                bfv8 a1  = *(const bfv8*)(ax + 16 * XW_LD + kk * 32);
                aq0 = MFMA(a0, wq, aq0);   aq1 = MFMA(a1, wq, aq1);
                ak0 = MFMA(a0, wk, ak0);   ak1 = MFMA(a1, wk, ak1);
                av0 = MFMA(wvv, a0, av0);  av1 = MFMA(wvv, a1, av1);  // swapped -> V^T
            }
            __builtin_amdgcn_s_setprio(0);
            const float SC = 0.17677669529663687f;
            const float bq = b_qkv[cQ + lr];
            const float bk = b_qkv[cK + lr];
            #pragma unroll
            for (int r = 0; r < 4; ++r) {
                const int t0 = mh * 32 + lg * 4 + r;
                sQ[(hh * 64 + t0) * QK_LD + dt * 16 + lr]      = (__bf16)((aq0[r] + bq) * SC);
                sQ[(hh * 64 + t0 + 16) * QK_LD + dt * 16 + lr] = (__bf16)((aq1[r] + bq) * SC);
                sK[(hh * 64 + t0) * QK_LD + dt * 16 + lr]      = (__bf16)(ak0[r] + bk);
                sK[(hh * 64 + t0 + 16) * QK_LD + dt * 16 + lr] = (__bf16)(ak1[r] + bk);
                const float bvr = b_qkv[cV + lg * 4 + r];
                sVT[(hh * 32 + dt * 16 + lg * 4 + r) * VT_LD + mh * 32 + lr]      = (__bf16)(av0[r] + bvr);
                sVT[(hh * 32 + dt * 16 + lg * 4 + r) * VT_LD + mh * 32 + 16 + lr] = (__bf16)(av1[r] + bvr);
            }
        }
        __syncthreads();

        // ---- attention: S^T = mfma(K,Q); lane owns one query row ----
        {
            const bfv8 qf = *(const bfv8*)&sQ[(ah * 64 + ms * 16 + lr) * QK_LD + k8];
            f32x4 st[4];
            __builtin_amdgcn_s_setprio(1);
            #pragma unroll
            for (int n = 0; n < 4; ++n) {
                bfv8 kf = *(const bfv8*)&sK[(ah * 64 + n * 16 + lr) * QK_LD + k8];
                f32x4 z{};
                st[n] = MFMA(kf, qf, z);
            }
            __builtin_amdgcn_s_setprio(0);
            float mx = -1e30f;
            #pragma unroll
            for (int n = 0; n < 4; ++n)
                #pragma unroll
                for (int r = 0; r < 4; ++r) mx = fmaxf(mx, st[n][r]);
            mx = fmaxf(mx, __shfl_xor(mx, 16, 64));
            mx = fmaxf(mx, __shfl_xor(mx, 32, 64));
            float sum = 0.f;
            #pragma unroll
            for (int n = 0; n < 4; ++n)
                #pragma unroll
                for (int r = 0; r < 4; ++r) { st[n][r] = __expf(st[n][r] - mx); sum += st[n][r]; }
            sum += __shfl_xor(sum, 16, 64);
            sum += __shfl_xor(sum, 32, 64);
            const float rinv = 1.f / sum;
            unsigned int pk[4][2];
            #pragma unroll
            for (int n = 0; n < 4; ++n) {
                pk[n][0] = pkbf(st[n][0] * rinv, st[n][1] * rinv);
                pk[n][1] = pkbf(st[n][2] * rinv, st[n][3] * rinv);
            }
            // P D-layout -> A-frag via bpermute:
            // dest lane (lg,lr) dword w <- lane (2(lg&1)+(w>>1))*16+lr, reg pk[2ks+(lg>>1)][w&1]
            const int abase = ((lg & 1) * 32 + lr) * 4;
            f32x4 o0{}, o1{};
            #pragma unroll
            for (int ks = 0; ks < 2; ++ks) {
                union { unsigned int u[4]; bfv8 v; } cv;
                #pragma unroll
                for (int w = 0; w < 4; ++w) {
                    const int addr = abase + (w >> 1) * 64;
                    const int lo_ = __builtin_amdgcn_ds_bpermute(addr, (int)pk[2 * ks][w & 1]);
                    const int hi_ = __builtin_amdgcn_ds_bpermute(addr, (int)pk[2 * ks + 1][w & 1]);
                    cv.u[w] = (unsigned int)((lg & 2) ? hi_ : lo_);
                }
                const bfv8 vf0 = *(const bfv8*)&sVT[(ah * 32 + lr) * VT_LD + ks * 32 + k8];
                const bfv8 vf1 = *(const bfv8*)&sVT[(ah * 32 + 16 + lr) * VT_LD + ks * 32 + k8];
                __builtin_amdgcn_s_setprio(1);
                o0 = MFMA(cv.v, vf0, o0);
                o1 = MFMA(cv.v, vf1, o1);
                __builtin_amdgcn_s_setprio(0);
            }
            opk[hp][0] = pkbf(o0[0], o0[1]);
            opk[hp][1] = pkbf(o0[2], o0[3]);
            opk[hp][2] = pkbf(o1[0], o1[1]);
            opk[hp][3] = pkbf(o1[2], o1[3]);
        }
        __syncthreads();   // before next hp's QKV overwrites sQ/sK/sVT
    }

    // ---- sX is dead: write attention output into it ----
    #pragma unroll
    for (int hp = 0; hp < 6; ++hp) {
        const int cb = (hp * 2 + ah) * 32;
        #pragma unroll
        for (int w = 0; w < 4; ++w) {
            const int colb = cb + (w >> 1) * 16 + lr;
            const int row0 = ms * 16 + lg * 4 + (w & 1) * 2;
            unsigned short lo = (unsigned short)(opk[hp][w] & 0xffff);
            unsigned short hi = (unsigned short)(opk[hp][w] >> 16);
            sX[row0 * XW_LD + colb]       = *(__bf16*)&lo;
            sX[(row0 + 1) * XW_LD + colb] = *(__bf16*)&hi;
        }
    }
    __syncthreads();

    // ---- projection: Out = O(64x384) @ Wp + b; wave = 3 n-tiles x 4 m-tiles ----
    {
        const int nb = wv * 48;
        const __bf16* bp0 = wprojT + (size_t)(nb + lr) * 384 + k8;
        const __bf16* bp1 = bp0 + (size_t)16 * 384;
        const __bf16* bp2 = bp0 + (size_t)32 * 384;
        f32x4 acc[4][3];
        #pragma unroll
        for (int m = 0; m < 4; ++m)
            #pragma unroll
            for (int j = 0; j < 3; ++j) acc[m][j] = f32x4{0.f, 0.f, 0.f, 0.f};
        #pragma unroll
        for (int kk = 0; kk < 12; ++kk) {
            const bfv8 b0 = *(const bfv8*)(bp0 + kk * 32);
            const bfv8 b1 = *(const bfv8*)(bp1 + kk * 32);
            const bfv8 b2 = *(const bfv8*)(bp2 + kk * 32);
            __builtin_amdgcn_s_setprio(1);
            #pragma unroll
            for (int m = 0; m < 4; ++m) {
                const bfv8 af = *(const bfv8*)&sX[(m * 16 + lr) * XW_LD + kk * 32 + k8];
                acc[m][0] = MFMA(af, b0, acc[m][0]);
                acc[m][1] = MFMA(af, b1, acc[m][1]);
                acc[m][2] = MFMA(af, b2, acc[m][2]);
            }
            __builtin_amdgcn_s_setprio(0);
        }
        float* ob = out + gbase;
        const float bb0 = b_proj[nb + lr], bb1 = b_proj[nb + 16 + lr], bb2 = b_proj[nb + 32 + lr];
        #pragma unroll
        for (int m = 0; m < 4; ++m)
            #pragma unroll
            for (int r = 0; r < 4; ++r) {
                const int t = m * 16 + lg * 4 + r;
                float* op = ob + (size_t)((t >> 3) * 64 + (t & 7)) * 384 + nb;
                op[lr]      = acc[m][0][r] + bb0;
                op[16 + lr] = acc[m][1][r] + bb1;
                op[32 + lr] = acc[m][2][r] + bb2;
            }
    }
}

extern "C" void kernel_launch(void* const* d_in, const int* in_sizes, int n_in,
                              void* d_out, int out_size, void* d_ws, size_t ws_size,
                              hipStream_t stream)
{
    const float* x      = (const float*)d_in[0];
    const float* w_qkv  = (const float*)d_in[1];
    const float* b_qkv  = (const float*)d_in[2];
    const float* w_proj = (const float*)d_in[3];
    const float* b_proj = (const float*)d_in[4];
    float* out = (float*)d_out;

    unsigned short* qT = (unsigned short*)d_ws;
    unsigned short* pT = qT + 1152 * 384;

    const int NPREP = 1152 * 384 + 384 * 384;
    prep_weights<<<(NPREP + 255) / 256, 256, 0, stream>>>(w_qkv, w_proj, qT, pT);
    win_attn<<<2048, 512, 0, stream>>>(x, b_qkv, b_proj, qT, pT, out);
}

// Round 4
// 412.654 us; speedup vs baseline: 1.4856x; 1.2597x over previous
//
#include <hip/hip_runtime.h>
#include <hip/hip_bf16.h>

typedef __bf16 bfv8 __attribute__((ext_vector_type(8)));
typedef float f32x4 __attribute__((ext_vector_type(4)));
typedef unsigned int u32;

#define MFMA(a,b,c) __builtin_amdgcn_mfma_f32_16x16x32_bf16((a),(b),(c),0,0,0)

constexpr int XW_LD = 392;   // 384+8 pad

// Transposed bf16 weights: qT[col][k] = w_qkv[k][col], pT[col][k] = w_proj[k][col]
__global__ __launch_bounds__(256)
void prep_weights(const float* __restrict__ w_qkv, const float* __restrict__ w_proj,
                  unsigned short* __restrict__ qT, unsigned short* __restrict__ pT)
{
    int i = blockIdx.x * 256 + threadIdx.x;
    const int NQ = 1152 * 384;
    if (i < NQ) {
        int c = i / 384, k = i - c * 384;
        __bf16 h = (__bf16)w_qkv[k * 1152 + c];
        qT[i] = *(unsigned short*)&h;
    } else {
        int j = i - NQ;
        if (j < 384 * 384) {
            int c = j / 384, k = j - c * 384;
            __bf16 h = (__bf16)w_proj[k * 384 + c];
            pT[j] = *(unsigned short*)&h;
        }
    }
}

__device__ __forceinline__ u32 pkbf(float a, float b) {
    __bf16 x = (__bf16)a, y = (__bf16)b;
    unsigned short lo = *(unsigned short*)&x, hi = *(unsigned short*)&y;
    return ((u32)hi << 16) | lo;
}

// Universal D-frag -> A/B-frag converter (HW-verified pattern from round 3):
// source = two 16x16 D-tiles along the frag's 32-long k-dim, packed as r-pairs
// (p00,p01 = tile0 dwords, p10,p11 = tile1). Dest dword w comes from lane
// (2*(lg&1)+(w>>1))*16+lr, packed dword (w&1), tile selected by lg&2.
__device__ __forceinline__ bfv8 conv_frag(u32 p00, u32 p01, u32 p10, u32 p11,
                                          int abase, bool selhi)
{
    union { u32 u[4]; bfv8 v; } cv;
    #pragma unroll
    for (int w = 0; w < 4; ++w) {
        const int addr = abase + (w >> 1) * 64;
        const int lo_ = __builtin_amdgcn_ds_bpermute(addr, (int)((w & 1) ? p01 : p00));
        const int hi_ = __builtin_amdgcn_ds_bpermute(addr, (int)((w & 1) ? p11 : p10));
        cv.u[w] = (u32)(selhi ? hi_ : lo_);
    }
    return cv.v;
}

// One WG (256 thr = 4 waves) per 8x8 window. Each wave owns 3 heads end-to-end
// with NO cross-wave sync: QKV via MFMA (Q^T,K^T swapped; V normal), all frag
// conversions in-register via conv_frag. 3 barriers total per WG.
// MFMA 16x16x32 layouts (m89/m92): a_frag lane(lg,lr) elem j = A[lr][k8+j];
// b_frag = B[k8+j][lr]; d lane reg r = D[lg*4+r][lr].
__global__ __launch_bounds__(256, 3)
void win_attn(const float* __restrict__ x,
              const float* __restrict__ b_qkv,
              const float* __restrict__ b_proj,
              const unsigned short* __restrict__ qT_,
              const unsigned short* __restrict__ pT_,
              float* __restrict__ out)
{
    __shared__ __bf16 sX[64 * XW_LD];   // 50176 B -> 3 WG/CU

    const __bf16* wqkvT  = (const __bf16*)qT_;
    const __bf16* wprojT = (const __bf16*)pT_;

    const int wid  = blockIdx.x;
    const int bb   = wid >> 6;
    const int wy   = (wid >> 3) & 7;
    const int wx   = wid & 7;
    const int tid  = threadIdx.x;
    const int lane = tid & 63;
    const int wv   = tid >> 6;          // wave 0..3
    const int lr   = lane & 15;
    const int lg   = lane >> 4;
    const int k8   = lg * 8;

    const size_t gbase = ((size_t)(bb * 64 + wy * 8) * 64 + wx * 8) * 384;

    // ---- stage x window -> sX bf16 ----
    {
        const float* xb = x + gbase;
        for (int i = tid; i < 64 * 96; i += 256) {
            int t  = i / 96;
            int c4 = (i - t * 96) * 4;
            const float4 v = *(const float4*)(xb + (size_t)((t >> 3) * 64 + (t & 7)) * 384 + c4);
            *(uint2*)&sX[t * XW_LD + c4] = make_uint2(pkbf(v.x, v.y), pkbf(v.z, v.w));
        }
    }
    __syncthreads();   // barrier 1

    const int   abase = ((lg & 1) * 32 + lr) * 4;
    const bool  selhi = (lg & 2) != 0;
    const float SC    = 0.17677669529663687f;   // 32^-0.5

    u32 opk[3][4][2][2];   // per-head attention output, packed bf16 (static idx only)

    #pragma unroll
    for (int hl = 0; hl < 3; ++hl) {
        const int h  = wv * 3 + hl;
        const int cQ = h * 32, cK = cQ + 384, cV = cQ + 768;

        // ---- QKV: Q^T,K^T = mfma(W-frag, x-frag); V = mfma(x-frag, W-frag) ----
        f32x4 aq[2][4], ak[2][4], av[4][2];
        #pragma unroll
        for (int a = 0; a < 2; ++a)
            #pragma unroll
            for (int b = 0; b < 4; ++b) { aq[a][b] = f32x4{0,0,0,0}; ak[a][b] = f32x4{0,0,0,0}; av[b][a] = f32x4{0,0,0,0}; }

        const __bf16* wqp = wqkvT + (size_t)(cQ + lr) * 384 + k8;
        const __bf16* wkp = wqkvT + (size_t)(cK + lr) * 384 + k8;
        const __bf16* wvp = wqkvT + (size_t)(cV + lr) * 384 + k8;
        const __bf16* xp  = &sX[lr * XW_LD + k8];

        #pragma unroll 2
        for (int kk = 0; kk < 12; ++kk) {
            bfv8 xf[4], wqf[2], wkf[2], wvf[2];
            #pragma unroll
            for (int t4 = 0; t4 < 4; ++t4) xf[t4] = *(const bfv8*)(xp + t4 * 16 * XW_LD + kk * 32);
            #pragma unroll
            for (int hdt = 0; hdt < 2; ++hdt) {
                wqf[hdt] = *(const bfv8*)(wqp + (size_t)hdt * 16 * 384 + kk * 32);
                wkf[hdt] = *(const bfv8*)(wkp + (size_t)hdt * 16 * 384 + kk * 32);
                wvf[hdt] = *(const bfv8*)(wvp + (size_t)hdt * 16 * 384 + kk * 32);
            }
            #pragma unroll
            for (int hdt = 0; hdt < 2; ++hdt)
                #pragma unroll
                for (int t4 = 0; t4 < 4; ++t4) {
                    aq[hdt][t4] = MFMA(wqf[hdt], xf[t4], aq[hdt][t4]);   // Q^T[hd][tok]
                    ak[hdt][t4] = MFMA(wkf[hdt], xf[t4], ak[hdt][t4]);   // K^T[hd][tok]
                    av[t4][hdt] = MFMA(xf[t4], wvf[hdt], av[t4][hdt]);   // V[tok][hd]
                }
        }

        // biases: Q^T/K^T rows = hd (lg*4+r); V cols = hd (lr)
        float bqv[2][4], bkv[2][4], bvv[2];
        #pragma unroll
        for (int hdt = 0; hdt < 2; ++hdt) {
            #pragma unroll
            for (int r = 0; r < 4; ++r) {
                bqv[hdt][r] = b_qkv[cQ + hdt * 16 + lg * 4 + r];
                bkv[hdt][r] = b_qkv[cK + hdt * 16 + lg * 4 + r];
            }
            bvv[hdt] = b_qkv[cV + hdt * 16 + lr];
        }

        // pack to bf16 r-pairs (Q gets SCALE folded in)
        u32 pkQ[2][4][2], pkK[2][4][2], pkV[4][2][2];
        #pragma unroll
        for (int hdt = 0; hdt < 2; ++hdt)
            #pragma unroll
            for (int t4 = 0; t4 < 4; ++t4)
                #pragma unroll
                for (int p = 0; p < 2; ++p) {
                    pkQ[hdt][t4][p] = pkbf((aq[hdt][t4][2 * p] + bqv[hdt][2 * p]) * SC,
                                           (aq[hdt][t4][2 * p + 1] + bqv[hdt][2 * p + 1]) * SC);
                    pkK[hdt][t4][p] = pkbf(ak[hdt][t4][2 * p] + bkv[hdt][2 * p],
                                           ak[hdt][t4][2 * p + 1] + bkv[hdt][2 * p + 1]);
                    pkV[t4][hdt][p] = pkbf(av[t4][hdt][2 * p] + bvv[hdt],
                                           av[t4][hdt][2 * p + 1] + bvv[hdt]);
                }

        // ---- S^T = mfma(K-frag, Q-frag): lane holds S[q=qt*16+lr][key=kt*16+lg*4+r] ----
        bfv8 Qf[4];
        #pragma unroll
        for (int qt = 0; qt < 4; ++qt)
            Qf[qt] = conv_frag(pkQ[0][qt][0], pkQ[0][qt][1], pkQ[1][qt][0], pkQ[1][qt][1], abase, selhi);
        f32x4 st[4][4];
        #pragma unroll
        for (int kt = 0; kt < 4; ++kt) {
            const bfv8 kf = conv_frag(pkK[0][kt][0], pkK[0][kt][1], pkK[1][kt][0], pkK[1][kt][1], abase, selhi);
            #pragma unroll
            for (int qt = 0; qt < 4; ++qt) {
                f32x4 z{};
                st[kt][qt] = MFMA(kf, Qf[qt], z);
            }
        }

        // ---- softmax per query (qt,lr): reduce over kt,r and lg-groups ----
        float rinv[4];
        #pragma unroll
        for (int qt = 0; qt < 4; ++qt) {
            float mx = -1e30f;
            #pragma unroll
            for (int kt = 0; kt < 4; ++kt)
                #pragma unroll
                for (int r = 0; r < 4; ++r) mx = fmaxf(mx, st[kt][qt][r]);
            mx = fmaxf(mx, __shfl_xor(mx, 16, 64));
            mx = fmaxf(mx, __shfl_xor(mx, 32, 64));
            float sum = 0.f;
            #pragma unroll
            for (int kt = 0; kt < 4; ++kt)
                #pragma unroll
                for (int r = 0; r < 4; ++r) { st[kt][qt][r] = __expf(st[kt][qt][r] - mx); sum += st[kt][qt][r]; }
            sum += __shfl_xor(sum, 16, 64);
            sum += __shfl_xor(sum, 32, 64);
            rinv[qt] = 1.f / sum;
        }
        u32 pkP[4][4][2];   // [qt][kt][p]
        #pragma unroll
        for (int qt = 0; qt < 4; ++qt)
            #pragma unroll
            for (int kt = 0; kt < 4; ++kt)
                #pragma unroll
                for (int p = 0; p < 2; ++p)
                    pkP[qt][kt][p] = pkbf(st[kt][qt][2 * p] * rinv[qt], st[kt][qt][2 * p + 1] * rinv[qt]);

        // ---- PV: O[q][hd] = P @ V ----
        bfv8 Vf[2][2];
        #pragma unroll
        for (int ks = 0; ks < 2; ++ks)
            #pragma unroll
            for (int hdt = 0; hdt < 2; ++hdt)
                Vf[ks][hdt] = conv_frag(pkV[2 * ks][hdt][0], pkV[2 * ks][hdt][1],
                                        pkV[2 * ks + 1][hdt][0], pkV[2 * ks + 1][hdt][1], abase, selhi);
        f32x4 o[4][2];
        #pragma unroll
        for (int qt = 0; qt < 4; ++qt)
            #pragma unroll
            for (int hdt = 0; hdt < 2; ++hdt) o[qt][hdt] = f32x4{0,0,0,0};
        #pragma unroll
        for (int qt = 0; qt < 4; ++qt)
            #pragma unroll
            for (int ks = 0; ks < 2; ++ks) {
                const bfv8 pf = conv_frag(pkP[qt][2 * ks][0], pkP[qt][2 * ks][1],
                                          pkP[qt][2 * ks + 1][0], pkP[qt][2 * ks + 1][1], abase, selhi);
                #pragma unroll
                for (int hdt = 0; hdt < 2; ++hdt)
                    o[qt][hdt] = MFMA(pf, Vf[ks][hdt], o[qt][hdt]);
            }
        #pragma unroll
        for (int qt = 0; qt < 4; ++qt)
            #pragma unroll
            for (int hdt = 0; hdt < 2; ++hdt)
                #pragma unroll
                for (int p = 0; p < 2; ++p)
                    opk[hl][qt][hdt][p] = pkbf(o[qt][hdt][2 * p], o[qt][hdt][2 * p + 1]);
    }

    __syncthreads();   // barrier 2: all waves done reading sX

    // ---- write O into sX (dead): row q, col h*32+hdt*16+lr ----
    #pragma unroll
    for (int hl = 0; hl < 3; ++hl)
        #pragma unroll
        for (int qt = 0; qt < 4; ++qt)
            #pragma unroll
            for (int hdt = 0; hdt < 2; ++hdt)
                #pragma unroll
                for (int p = 0; p < 2; ++p) {
                    const u32 u = opk[hl][qt][hdt][p];
                    const int row0 = qt * 16 + lg * 4 + 2 * p;
                    const int col  = (wv * 3 + hl) * 32 + hdt * 16 + lr;
                    unsigned short lo = (unsigned short)(u & 0xffff);
                    unsigned short hi = (unsigned short)(u >> 16);
                    sX[row0 * XW_LD + col]       = *(__bf16*)&lo;
                    sX[(row0 + 1) * XW_LD + col] = *(__bf16*)&hi;
                }
    __syncthreads();   // barrier 3

    // ---- projection: Out = O(64x384) @ Wp + b; wave = 6 n-tiles x 4 m-tiles ----
    {
        const int nb = wv * 96;
        const __bf16* bp = wprojT + (size_t)(nb + lr) * 384 + k8;
        f32x4 acc[4][6];
        #pragma unroll
        for (int m = 0; m < 4; ++m)
            #pragma unroll
            for (int nt = 0; nt < 6; ++nt) acc[m][nt] = f32x4{0,0,0,0};
        #pragma unroll 2
        for (int kk = 0; kk < 12; ++kk) {
            bfv8 bfr[6];
            #pragma unroll
            for (int nt = 0; nt < 6; ++nt)
                bfr[nt] = *(const bfv8*)(bp + (size_t)nt * 16 * 384 + kk * 32);
            #pragma unroll
            for (int m = 0; m < 4; ++m) {
                const bfv8 af = *(const bfv8*)&sX[(m * 16 + lr) * XW_LD + kk * 32 + k8];
                #pragma unroll
                for (int nt = 0; nt < 6; ++nt)
                    acc[m][nt] = MFMA(af, bfr[nt], acc[m][nt]);
            }
        }
        float bpj[6];
        #pragma unroll
        for (int nt = 0; nt < 6; ++nt) bpj[nt] = b_proj[nb + nt * 16 + lr];
        float* ob = out + gbase;
        #pragma unroll
        for (int m = 0; m < 4; ++m)
            #pragma unroll
            for (int r = 0; r < 4; ++r) {
                const int t = m * 16 + lg * 4 + r;
                float* op = ob + (size_t)((t >> 3) * 64 + (t & 7)) * 384 + nb;
                #pragma unroll
                for (int nt = 0; nt < 6; ++nt)
                    op[nt * 16 + lr] = acc[m][nt][r] + bpj[nt];
            }
    }
}

extern "C" void kernel_launch(void* const* d_in, const int* in_sizes, int n_in,
                              void* d_out, int out_size, void* d_ws, size_t ws_size,
                              hipStream_t stream)
{
    const float* x      = (const float*)d_in[0];
    const float* w_qkv  = (const float*)d_in[1];
    const float* b_qkv  = (const float*)d_in[2];
    const float* w_proj = (const float*)d_in[3];
    const float* b_proj = (const float*)d_in[4];
    float* out = (float*)d_out;

    unsigned short* qT = (unsigned short*)d_ws;
    unsigned short* pT = qT + 1152 * 384;

    const int NPREP = 1152 * 384 + 384 * 384;
    prep_weights<<<(NPREP + 255) / 256, 256, 0, stream>>>(w_qkv, w_proj, qT, pT);
    win_attn<<<2048, 256, 0, stream>>>(x, b_qkv, b_proj, qT, pT, out);
}

// Round 5
// 382.193 us; speedup vs baseline: 1.6040x; 1.0797x over previous
//
#include <hip/hip_runtime.h>
#include <hip/hip_bf16.h>

typedef __bf16 bfv8 __attribute__((ext_vector_type(8)));
typedef float f32x4 __attribute__((ext_vector_type(4)));
typedef unsigned int u32;

#define MFMA(a,b,c) __builtin_amdgcn_mfma_f32_16x16x32_bf16((a),(b),(c),0,0,0)

constexpr int XW_LD = 392;   // 384+8 pad

// Transposed bf16 weights: qT[col][k] = w_qkv[k][col], pT[col][k] = w_proj[k][col]
__global__ __launch_bounds__(256)
void prep_weights(const float* __restrict__ w_qkv, const float* __restrict__ w_proj,
                  unsigned short* __restrict__ qT, unsigned short* __restrict__ pT)
{
    int i = blockIdx.x * 256 + threadIdx.x;
    const int NQ = 1152 * 384;
    if (i < NQ) {
        int c = i / 384, k = i - c * 384;
        __bf16 h = (__bf16)w_qkv[k * 1152 + c];
        qT[i] = *(unsigned short*)&h;
    } else {
        int j = i - NQ;
        if (j < 384 * 384) {
            int c = j / 384, k = j - c * 384;
            __bf16 h = (__bf16)w_proj[k * 384 + c];
            pT[j] = *(unsigned short*)&h;
        }
    }
}

__device__ __forceinline__ u32 pkbf(float a, float b) {
    __bf16 x = (__bf16)a, y = (__bf16)b;
    unsigned short lo = *(unsigned short*)&x, hi = *(unsigned short*)&y;
    return ((u32)hi << 16) | lo;
}

// Universal D-frag -> A/B-frag converter (HW-verified round 3/4):
// dest lane (lg,lr) dword w <- lane (2*(lg&1)+(w>>1))*16+lr, packed dword (w&1),
// tile pair selected by lg&2.
__device__ __forceinline__ bfv8 conv_frag(u32 p00, u32 p01, u32 p10, u32 p11,
                                          int abase, bool selhi)
{
    union { u32 u[4]; bfv8 v; } cv;
    #pragma unroll
    for (int w = 0; w < 4; ++w) {
        const int addr = abase + (w >> 1) * 64;
        const int lo_ = __builtin_amdgcn_ds_bpermute(addr, (int)((w & 1) ? p01 : p00));
        const int hi_ = __builtin_amdgcn_ds_bpermute(addr, (int)((w & 1) ? p11 : p10));
        cv.u[w] = (u32)(selhi ? hi_ : lo_);
    }
    return cv.v;
}

// One WG (256 thr = 4 waves) per 8x8 window; wave owns 3 heads end-to-end.
// Head loop ROLLED (code must fit 32KB I$); opk -> 96B/lane scratch (cold).
// MFMA 16x16x32 layouts (m89/m92): a_frag lane(lg,lr) elem j = A[lr][k8+j];
// b_frag = B[k8+j][lr]; d lane reg r = D[lg*4+r][lr].
__global__ __launch_bounds__(256, 3)
void win_attn(const float* __restrict__ x,
              const float* __restrict__ b_qkv,
              const float* __restrict__ b_proj,
              const unsigned short* __restrict__ qT_,
              const unsigned short* __restrict__ pT_,
              float* __restrict__ out)
{
    __shared__ __bf16 sX[64 * XW_LD];   // 50176 B -> 3 WG/CU (LDS-capped occupancy)

    const __bf16* wqkvT  = (const __bf16*)qT_;
    const __bf16* wprojT = (const __bf16*)pT_;

    const int wid  = blockIdx.x;
    const int bb   = wid >> 6;
    const int wy   = (wid >> 3) & 7;
    const int wx   = wid & 7;
    const int tid  = threadIdx.x;
    const int lane = tid & 63;
    const int wv   = tid >> 6;          // wave 0..3
    const int lr   = lane & 15;
    const int lg   = lane >> 4;
    const int k8   = lg * 8;

    const size_t gbase = ((size_t)(bb * 64 + wy * 8) * 64 + wx * 8) * 384;

    // ---- stage x window -> sX bf16 ----
    {
        const float* xb = x + gbase;
        for (int i = tid; i < 64 * 96; i += 256) {
            int t  = i / 96;
            int c4 = (i - t * 96) * 4;
            const float4 v = *(const float4*)(xb + (size_t)((t >> 3) * 64 + (t & 7)) * 384 + c4);
            *(uint2*)&sX[t * XW_LD + c4] = make_uint2(pkbf(v.x, v.y), pkbf(v.z, v.w));
        }
    }
    __syncthreads();   // barrier 1

    const int   abase = ((lg & 1) * 32 + lr) * 4;
    const bool  selhi = (lg & 2) != 0;
    const float SC    = 0.17677669529663687f;   // 32^-0.5

    u32 opk[3][4][2][2];   // runtime-hl indexed -> scratch (96B/lane, cold)

    #pragma unroll 1
    for (int hl = 0; hl < 3; ++hl) {
        const int h  = wv * 3 + hl;
        const int cQ = h * 32, cK = cQ + 384, cV = cQ + 768;

        // ---- QKV: Q^T,K^T = mfma(W-frag, x-frag); V = mfma(x-frag, W-frag) ----
        f32x4 aq[2][4], ak[2][4], av[4][2];
        #pragma unroll
        for (int a = 0; a < 2; ++a)
            #pragma unroll
            for (int b = 0; b < 4; ++b) { aq[a][b] = f32x4{0,0,0,0}; ak[a][b] = f32x4{0,0,0,0}; av[b][a] = f32x4{0,0,0,0}; }

        const __bf16* wqp = wqkvT + (size_t)(cQ + lr) * 384 + k8;
        const __bf16* wkp = wqkvT + (size_t)(cK + lr) * 384 + k8;
        const __bf16* wvp = wqkvT + (size_t)(cV + lr) * 384 + k8;
        const __bf16* xp  = &sX[lr * XW_LD + k8];

        __builtin_amdgcn_s_setprio(1);
        #pragma unroll 2
        for (int kk = 0; kk < 12; ++kk) {
            bfv8 xf[4], wqf[2], wkf[2], wvf[2];
            #pragma unroll
            for (int t4 = 0; t4 < 4; ++t4) xf[t4] = *(const bfv8*)(xp + t4 * 16 * XW_LD + kk * 32);
            #pragma unroll
            for (int hdt = 0; hdt < 2; ++hdt) {
                wqf[hdt] = *(const bfv8*)(wqp + (size_t)hdt * 16 * 384 + kk * 32);
                wkf[hdt] = *(const bfv8*)(wkp + (size_t)hdt * 16 * 384 + kk * 32);
                wvf[hdt] = *(const bfv8*)(wvp + (size_t)hdt * 16 * 384 + kk * 32);
            }
            #pragma unroll
            for (int hdt = 0; hdt < 2; ++hdt)
                #pragma unroll
                for (int t4 = 0; t4 < 4; ++t4) {
                    aq[hdt][t4] = MFMA(wqf[hdt], xf[t4], aq[hdt][t4]);   // Q^T[hd][tok]
                    ak[hdt][t4] = MFMA(wkf[hdt], xf[t4], ak[hdt][t4]);   // K^T[hd][tok]
                    av[t4][hdt] = MFMA(xf[t4], wvf[hdt], av[t4][hdt]);   // V[tok][hd]
                }
        }
        __builtin_amdgcn_s_setprio(0);

        // biases: Q^T/K^T rows = hd (lg*4+r); V cols = hd (lr)
        float bqv[2][4], bkv[2][4], bvv[2];
        #pragma unroll
        for (int hdt = 0; hdt < 2; ++hdt) {
            #pragma unroll
            for (int r = 0; r < 4; ++r) {
                bqv[hdt][r] = b_qkv[cQ + hdt * 16 + lg * 4 + r];
                bkv[hdt][r] = b_qkv[cK + hdt * 16 + lg * 4 + r];
            }
            bvv[hdt] = b_qkv[cV + hdt * 16 + lr];
        }

        // pack to bf16 r-pairs (Q gets SCALE folded in)
        u32 pkQ[2][4][2], pkK[2][4][2], pkV[4][2][2];
        #pragma unroll
        for (int hdt = 0; hdt < 2; ++hdt)
            #pragma unroll
            for (int t4 = 0; t4 < 4; ++t4)
                #pragma unroll
                for (int p = 0; p < 2; ++p) {
                    pkQ[hdt][t4][p] = pkbf((aq[hdt][t4][2 * p] + bqv[hdt][2 * p]) * SC,
                                           (aq[hdt][t4][2 * p + 1] + bqv[hdt][2 * p + 1]) * SC);
                    pkK[hdt][t4][p] = pkbf(ak[hdt][t4][2 * p] + bkv[hdt][2 * p],
                                           ak[hdt][t4][2 * p + 1] + bkv[hdt][2 * p + 1]);
                    pkV[t4][hdt][p] = pkbf(av[t4][hdt][2 * p] + bvv[hdt],
                                           av[t4][hdt][2 * p + 1] + bvv[hdt]);
                }

        // ---- S^T = mfma(K-frag, Q-frag): lane holds S[q=qt*16+lr][key=kt*16+lg*4+r] ----
        bfv8 Qf[4];
        #pragma unroll
        for (int qt = 0; qt < 4; ++qt)
            Qf[qt] = conv_frag(pkQ[0][qt][0], pkQ[0][qt][1], pkQ[1][qt][0], pkQ[1][qt][1], abase, selhi);
        f32x4 st[4][4];
        __builtin_amdgcn_s_setprio(1);
        #pragma unroll
        for (int kt = 0; kt < 4; ++kt) {
            const bfv8 kf = conv_frag(pkK[0][kt][0], pkK[0][kt][1], pkK[1][kt][0], pkK[1][kt][1], abase, selhi);
            #pragma unroll
            for (int qt = 0; qt < 4; ++qt) {
                f32x4 z{};
                st[kt][qt] = MFMA(kf, Qf[qt], z);
            }
        }
        __builtin_amdgcn_s_setprio(0);

        // ---- softmax per query (qt,lr): reduce over kt,r and lg-groups ----
        float rinv[4];
        #pragma unroll
        for (int qt = 0; qt < 4; ++qt) {
            float mx = -1e30f;
            #pragma unroll
            for (int kt = 0; kt < 4; ++kt)
                #pragma unroll
                for (int r = 0; r < 4; ++r) mx = fmaxf(mx, st[kt][qt][r]);
            mx = fmaxf(mx, __shfl_xor(mx, 16, 64));
            mx = fmaxf(mx, __shfl_xor(mx, 32, 64));
            float sum = 0.f;
            #pragma unroll
            for (int kt = 0; kt < 4; ++kt)
                #pragma unroll
                for (int r = 0; r < 4; ++r) { st[kt][qt][r] = __expf(st[kt][qt][r] - mx); sum += st[kt][qt][r]; }
            sum += __shfl_xor(sum, 16, 64);
            sum += __shfl_xor(sum, 32, 64);
            rinv[qt] = 1.f / sum;
        }
        u32 pkP[4][4][2];   // [qt][kt][p]
        #pragma unroll
        for (int qt = 0; qt < 4; ++qt)
            #pragma unroll
            for (int kt = 0; kt < 4; ++kt)
                #pragma unroll
                for (int p = 0; p < 2; ++p)
                    pkP[qt][kt][p] = pkbf(st[kt][qt][2 * p] * rinv[qt], st[kt][qt][2 * p + 1] * rinv[qt]);

        // ---- PV: O[q][hd] = P @ V ----
        bfv8 Vf[2][2];
        #pragma unroll
        for (int ks = 0; ks < 2; ++ks)
            #pragma unroll
            for (int hdt = 0; hdt < 2; ++hdt)
                Vf[ks][hdt] = conv_frag(pkV[2 * ks][hdt][0], pkV[2 * ks][hdt][1],
                                        pkV[2 * ks + 1][hdt][0], pkV[2 * ks + 1][hdt][1], abase, selhi);
        f32x4 o[4][2];
        #pragma unroll
        for (int qt = 0; qt < 4; ++qt)
            #pragma unroll
            for (int hdt = 0; hdt < 2; ++hdt) o[qt][hdt] = f32x4{0,0,0,0};
        __builtin_amdgcn_s_setprio(1);
        #pragma unroll
        for (int qt = 0; qt < 4; ++qt)
            #pragma unroll
            for (int ks = 0; ks < 2; ++ks) {
                const bfv8 pf = conv_frag(pkP[qt][2 * ks][0], pkP[qt][2 * ks][1],
                                          pkP[qt][2 * ks + 1][0], pkP[qt][2 * ks + 1][1], abase, selhi);
                #pragma unroll
                for (int hdt = 0; hdt < 2; ++hdt)
                    o[qt][hdt] = MFMA(pf, Vf[ks][hdt], o[qt][hdt]);
            }
        __builtin_amdgcn_s_setprio(0);
        #pragma unroll
        for (int qt = 0; qt < 4; ++qt)
            #pragma unroll
            for (int hdt = 0; hdt < 2; ++hdt)
                #pragma unroll
                for (int p = 0; p < 2; ++p)
                    opk[hl][qt][hdt][p] = pkbf(o[qt][hdt][2 * p], o[qt][hdt][2 * p + 1]);
    }

    __syncthreads();   // barrier 2: all waves done reading sX (x data)

    // ---- write O into sX (dead): row q, col h*32+hdt*16+lr ----
    #pragma unroll
    for (int hl = 0; hl < 3; ++hl)
        #pragma unroll
        for (int qt = 0; qt < 4; ++qt)
            #pragma unroll
            for (int hdt = 0; hdt < 2; ++hdt)
                #pragma unroll
                for (int p = 0; p < 2; ++p) {
                    const u32 u = opk[hl][qt][hdt][p];
                    const int row0 = qt * 16 + lg * 4 + 2 * p;
                    const int col  = (wv * 3 + hl) * 32 + hdt * 16 + lr;
                    unsigned short lo = (unsigned short)(u & 0xffff);
                    unsigned short hi = (unsigned short)(u >> 16);
                    sX[row0 * XW_LD + col]       = *(__bf16*)&lo;
                    sX[(row0 + 1) * XW_LD + col] = *(__bf16*)&hi;
                }
    __syncthreads();   // barrier 3

    // ---- projection: Out = O(64x384) @ Wp + b; wave = 6 n-tiles x 4 m-tiles ----
    const int nb = wv * 96;
    f32x4 acc[4][6];
    {
        const __bf16* bp = wprojT + (size_t)(nb + lr) * 384 + k8;
        #pragma unroll
        for (int m = 0; m < 4; ++m)
            #pragma unroll
            for (int nt = 0; nt < 6; ++nt) acc[m][nt] = f32x4{0,0,0,0};
        __builtin_amdgcn_s_setprio(1);
        #pragma unroll 2
        for (int kk = 0; kk < 12; ++kk) {
            bfv8 bfr[6];
            #pragma unroll
            for (int nt = 0; nt < 6; ++nt)
                bfr[nt] = *(const bfv8*)(bp + (size_t)nt * 16 * 384 + kk * 32);
            #pragma unroll
            for (int m = 0; m < 4; ++m) {
                const bfv8 af = *(const bfv8*)&sX[(m * 16 + lr) * XW_LD + kk * 32 + k8];
                #pragma unroll
                for (int nt = 0; nt < 6; ++nt)
                    acc[m][nt] = MFMA(af, bfr[nt], acc[m][nt]);
            }
        }
        __builtin_amdgcn_s_setprio(0);
    }
    float bpj[6];
    #pragma unroll
    for (int nt = 0; nt < 6; ++nt) bpj[nt] = b_proj[nb + nt * 16 + lr];

    // ---- coalesced output: stage 32 rows (f32) in sX, store full 1536B rows ----
    __syncthreads();   // barrier 4: all proj reads of sX complete
    float* sF = (float*)sX;            // 32 rows x 384 f32 = 49152 B <= 50176
    float* ob = out + gbase;
    #pragma unroll
    for (int half = 0; half < 2; ++half) {
        #pragma unroll
        for (int mm = 0; mm < 2; ++mm) {
            const int m = half * 2 + mm;
            #pragma unroll
            for (int r = 0; r < 4; ++r) {
                const int row = mm * 16 + lg * 4 + r;   // 0..31 within half
                #pragma unroll
                for (int nt = 0; nt < 6; ++nt)
                    sF[row * 384 + nb + nt * 16 + lr] = acc[m][nt][r] + bpj[nt];
            }
        }
        __syncthreads();   // staging visible to all
        for (int i = tid; i < 32 * 96; i += 256) {
            const int row = i / 96;
            const int c4  = (i - row * 96) * 4;
            const int t   = half * 32 + row;
            const float4 v = *(const float4*)&sF[row * 384 + c4];
            *(float4*)(ob + (size_t)((t >> 3) * 64 + (t & 7)) * 384 + c4) = v;
        }
        if (half == 0) __syncthreads();   // stores done before half-1 staging
    }
}

extern "C" void kernel_launch(void* const* d_in, const int* in_sizes, int n_in,
                              void* d_out, int out_size, void* d_ws, size_t ws_size,
                              hipStream_t stream)
{
    const float* x      = (const float*)d_in[0];
    const float* w_qkv  = (const float*)d_in[1];
    const float* b_qkv  = (const float*)d_in[2];
    const float* w_proj = (const float*)d_in[3];
    const float* b_proj = (const float*)d_in[4];
    float* out = (float*)d_out;

    unsigned short* qT = (unsigned short*)d_ws;
    unsigned short* pT = qT + 1152 * 384;

    const int NPREP = 1152 * 384 + 384 * 384;
    prep_weights<<<(NPREP + 255) / 256, 256, 0, stream>>>(w_qkv, w_proj, qT, pT);
    win_attn<<<2048, 256, 0, stream>>>(x, b_qkv, b_proj, qT, pT, out);
}